// Round 10
// baseline (136.380 us; speedup 1.0000x reference)
//
#include <hip/hip_runtime.h>
#include <hip/hip_bf16.h>
#include <math.h>

#define B_ 4
#define L_ 1024
#define H_ 8
#define E_ 64
#define N_ 1024
#define NF_ 513            // rfft bins for N=1024
#define SCALE_ 0.125f      // 1/sqrt(E)
#define HE_ (H_ * E_)
#define ZP_ 1104           // padded float2 slots for 1024 points (PD(1023)=1101)

typedef _Float16 f16x8 __attribute__((ext_vector_type(8)));
typedef float f32x4 __attribute__((ext_vector_type(4)));

// base-4 digit reversal of a 10-bit index (5 digits); involution.
__device__ __forceinline__ int dr4(int x) {
    const int r = (int)(__brev((unsigned)x) >> 22);   // bit-reverse 10 bits
    return ((r & 0x155) << 1) | ((r >> 1) & 0x155);   // swap adjacent bits
}

// Padded LDS index: kills power-of-2 stride bank conflicts (<=2-way, free).
__device__ __forceinline__ int PD(int i) { return i + (i >> 4) + (i >> 6); }

// w = (cos, sin); multiply v by exp(dir*i*theta).
__device__ __forceinline__ float2 cmulw(float2 v, float2 w, float dir) {
    const float wi = dir * w.y;
    return make_float2(v.x * w.x - v.y * wi, v.x * wi + v.y * w.x);
}

// radix-4 combine: y_q = sum_m x_m * W4^{q*m}, W4 = exp(dir*i*pi/2).
__device__ __forceinline__ void r4c(const float2 x0, const float2 x1,
                                    const float2 x2, const float2 x3,
                                    const float dir,
                                    float2& y0, float2& y1, float2& y2, float2& y3) {
    const float ax = x0.x + x2.x, ay = x0.y + x2.y;
    const float bx = x0.x - x2.x, by = x0.y - x2.y;
    const float cx = x1.x + x3.x, cy = x1.y + x3.y;
    const float dx = x1.x - x3.x, dy = x1.y - x3.y;
    y0 = make_float2(ax + cx, ay + cy);
    y2 = make_float2(ax - cx, ay - cy);
    y1 = make_float2(bx - dir * dy, by + dir * dx);
    y3 = make_float2(bx + dir * dy, by - dir * dx);
}

// Twiddle table at padded slots: tw[PD(k)] = (cos, sin)(2*pi*k/1024).
__device__ __forceinline__ void fill_tw(float2* tw, int t) {
    for (int i = t; i < 1024; i += 256) {
        float sv, cv;
        sincosf(6.283185307179586f * (float)i / 1024.0f, &sv, &cv);
        tw[PD(i)] = make_float2(cv, sv);
    }
}

// ---- Wave-private radix-4 FFT: 64 lanes x 16 points, NO s_barrier ----
// DS ops within a wave execute in order at the LDS pipe; wave_barrier()
// (zero-cost) stops the compiler from reordering across stages.
// DIT: digit-reversed input -> natural output.
__device__ __forceinline__ void wfft_dit4(float2* z, const float2* tw, int lane, float dir) {
    #pragma unroll
    for (int st = 0; st < 5; ++st) {
        const int l2q = 2 * st, qs = 1 << l2q;
        const int step = 1 << (8 - l2q);
        #pragma unroll
        for (int ib = 0; ib < 4; ++ib) {
            const int j = lane + 64 * ib;
            const int pos = j & (qs - 1);
            const int base = ((j >> l2q) << (l2q + 2)) + pos;
            const int i0 = PD(base), i1 = PD(base + qs), i2 = PD(base + 2 * qs), i3 = PD(base + 3 * qs);
            float2 x0 = z[i0], x1 = z[i1], x2 = z[i2], x3 = z[i3];
            if (st) {
                x1 = cmulw(x1, tw[PD(pos * step)], dir);
                x2 = cmulw(x2, tw[PD(2 * pos * step)], dir);
                x3 = cmulw(x3, tw[PD(3 * pos * step)], dir);
            }
            float2 y0, y1, y2, y3;
            r4c(x0, x1, x2, x3, dir, y0, y1, y2, y3);
            z[i0] = y0; z[i1] = y1; z[i2] = y2; z[i3] = y3;
        }
        __builtin_amdgcn_wave_barrier();
    }
}

// DIF: natural input -> digit-reversed output.
__device__ __forceinline__ void wfft_dif4(float2* z, const float2* tw, int lane, float dir) {
    #pragma unroll
    for (int st = 4; st >= 0; --st) {
        const int l2q = 2 * st, qs = 1 << l2q;
        const int step = 1 << (8 - l2q);
        #pragma unroll
        for (int ib = 0; ib < 4; ++ib) {
            const int j = lane + 64 * ib;
            const int pos = j & (qs - 1);
            const int base = ((j >> l2q) << (l2q + 2)) + pos;
            const int i0 = PD(base), i1 = PD(base + qs), i2 = PD(base + 2 * qs), i3 = PD(base + 3 * qs);
            const float2 x0 = z[i0], x1 = z[i1], x2 = z[i2], x3 = z[i3];
            float2 s0, s1, s2, s3;
            r4c(x0, x1, x2, x3, dir, s0, s1, s2, s3);
            if (st) {
                s1 = cmulw(s1, tw[PD(pos * step)], dir);
                s2 = cmulw(s2, tw[PD(2 * pos * step)], dir);
                s3 = cmulw(s3, tw[PD(3 * pos * step)], dir);
            }
            z[i0] = s0; z[i1] = s1; z[i2] = s2; z[i3] = s3;
        }
        __builtin_amdgcn_wave_barrier();
    }
}

// Kernel 0: K rows -> unit-normalized f16 (Kh). (Q norms now inline in k_qkfft.)
__global__ __launch_bounds__(256) void k_prep(const float* __restrict__ K,
                                              _Float16* __restrict__ Kh) {
    const int i = blockIdx.x * 256 + threadIdx.x;
    if (i >= B_ * L_ * H_) return;
    const float* p = K + (size_t)i * E_;
    float ss = 0.0f;
    #pragma unroll
    for (int j = 0; j < 16; ++j) {
        const float4 v = *(const float4*)(p + j * 4);
        ss += v.x * v.x + v.y * v.y + v.z * v.z + v.w * v.w;
    }
    const float r = rsqrtf(ss);
    _Float16* out = Kh + (size_t)i * E_;
    #pragma unroll
    for (int e = 0; e < E_; e += 8) {
        const float4 x = *(const float4*)(p + e);
        const float4 y = *(const float4*)(p + e + 4);
        f16x8 o;
        o[0] = (_Float16)(x.x * r); o[1] = (_Float16)(x.y * r);
        o[2] = (_Float16)(x.z * r); o[3] = (_Float16)(x.w * r);
        o[4] = (_Float16)(y.x * r); o[5] = (_Float16)(y.y * r);
        o[6] = (_Float16)(y.z * r); o[7] = (_Float16)(y.w * r);
        *(f16x8*)(out + e) = o;
    }
}

// Kernel 1: block = one (b,h) x 16 q-rows. MFMA QK^T (slot j <- K row dr4(j)),
// then 2 rounds x {scatter (2 barriers), WAVE-PRIVATE pair-FFT (0 barriers),
// wave-local softmax (DC = exact row max, 6 shuffles)}; per-lane register
// accumulators merged once via LDS float atomics at the end. ~5 block
// barriers total vs ~16 in round 9.
__global__ __attribute__((amdgpu_flat_work_group_size(256, 256), amdgpu_waves_per_eu(2, 3)))
void k_qkfft(const float* __restrict__ Q,
             const _Float16* __restrict__ Kh,
             float* __restrict__ G) {
    __shared__ float2 s_z[4 * ZP_];   // 4 padded FFT buffers (35.3 KB)
    __shared__ float2 s_tw[ZP_];      // padded twiddles (8.8 KB)
    __shared__ float s_acc[NF_];

    const int t = threadIdx.x;
    const int bid = blockIdx.x;
    const int bh = bid >> 6;        // consecutive blocks share (b,h) -> L2 reuse of Kh
    const int chunk = bid & 63;
    const int b = bh >> 3, h = bh & 7;
    const int l0 = chunk * 16;

    const int c = t & 15;           // A-row / B-col within 16-tile
    const int g = (t >> 4) & 3;     // k-group of the fragment / acc row-group
    const int w = t >> 6;           // wave id; wave w owns FFT buffer w
    const int lane = t & 63;

    fill_tw(s_tw, t);
    for (int kk = t; kk < NF_; kk += 256) s_acc[kk] = 0.0f;

    // ---- A fragments: q-row (l0+c); norm computed inline (2 shuffles) ----
    const float* qrow = Q + (((size_t)b * L_ + l0 + c) * H_ + h) * E_;
    const float4 x0 = *(const float4*)(qrow + g * 8);
    const float4 y0 = *(const float4*)(qrow + g * 8 + 4);
    const float4 x1 = *(const float4*)(qrow + 32 + g * 8);
    const float4 y1 = *(const float4*)(qrow + 32 + g * 8 + 4);
    float ss = x0.x * x0.x + x0.y * x0.y + x0.z * x0.z + x0.w * x0.w
             + y0.x * y0.x + y0.y * y0.y + y0.z * y0.z + y0.w * y0.w
             + x1.x * x1.x + x1.y * x1.y + x1.z * x1.z + x1.w * x1.w
             + y1.x * y1.x + y1.y * y1.y + y1.z * y1.z + y1.w * y1.w;
    ss += __shfl_xor(ss, 16);
    ss += __shfl_xor(ss, 32);       // lanes {c, c+16, c+32, c+48} share a row
    const float qn = rsqrtf(ss);
    f16x8 af0, af1;
    af0[0] = (_Float16)(x0.x * qn); af0[1] = (_Float16)(x0.y * qn);
    af0[2] = (_Float16)(x0.z * qn); af0[3] = (_Float16)(x0.w * qn);
    af0[4] = (_Float16)(y0.x * qn); af0[5] = (_Float16)(y0.y * qn);
    af0[6] = (_Float16)(y0.z * qn); af0[7] = (_Float16)(y0.w * qn);
    af1[0] = (_Float16)(x1.x * qn); af1[1] = (_Float16)(x1.y * qn);
    af1[2] = (_Float16)(x1.z * qn); af1[3] = (_Float16)(x1.w * qn);
    af1[4] = (_Float16)(y1.x * qn); af1[5] = (_Float16)(y1.y * qn);
    af1[6] = (_Float16)(y1.z * qn); af1[7] = (_Float16)(y1.w * qn);

    // ---- B fragments + MFMA: 16 N-tiles, 2 k-steps each ----
    f32x4 acc[16];
    #pragma unroll
    for (int n = 0; n < 16; ++n) acc[n] = (f32x4){0.0f, 0.0f, 0.0f, 0.0f};

    #pragma unroll
    for (int n = 0; n < 16; ++n) {
        const int j = w * 256 + n * 16 + c;
        const int s = dr4(j);
        const f16x8* bp = (const f16x8*)(Kh + (((size_t)b * L_ + s) * H_ + h) * E_);
        const f16x8 b0 = bp[g];
        const f16x8 b1 = bp[4 + g];
        acc[n] = __builtin_amdgcn_mfma_f32_16x16x32_f16(af0, b0, acc[n], 0, 0, 0);
        acc[n] = __builtin_amdgcn_mfma_f32_16x16x32_f16(af1, b1, acc[n], 0, 0, 0);
        if ((n & 3) == 3) __builtin_amdgcn_sched_barrier(0);  // fence load hoisting
    }

    // sim = exp(cos) in place
    #pragma unroll
    for (int n = 0; n < 16; ++n) {
        #pragma unroll
        for (int r = 0; r < 4; ++r) acc[n][r] = __expf(acc[n][r]);
    }

    // per-lane softmax-normalized accumulators (registers, both rounds)
    float gacc[8];
    #pragma unroll
    for (int ib = 0; ib < 8; ++ib) gacc[ib] = 0.0f;
    float gN = 0.0f;

    float2* zw = s_z + w * ZP_;     // this wave's FFT buffer
    const float dir = -1.0f;

    #pragma unroll
    for (int rr = 0; rr < 2; ++rr) {
        __syncthreads();   // (A) prior-round buffer reads done (rr=0: tw/acc init)
        {
            const int gq = g - 2 * rr;   // rows 8rr..8rr+7 live in g = 2rr, 2rr+1
            if (gq == 0 || gq == 1) {
                float2* z01 = s_z + (2 * gq) * ZP_;
                #pragma unroll
                for (int n = 0; n < 16; ++n) {
                    const int ps = PD(w * 256 + n * 16 + c);
                    z01[ps]       = make_float2(acc[n][0], acc[n][1]);
                    z01[ZP_ + ps] = make_float2(acc[n][2], acc[n][3]);
                }
            }
        }
        __syncthreads();   // (B) scatter visible to all waves

        wfft_dit4(zw, s_tw, lane, dir);   // wave-private, 0 barriers

        // wave-local softmax: rows A (.x) and B (.y); max = DC bin (exact)
        const float mA = SCALE_ * zw[0].x;
        const float mB = SCALE_ * zw[0].y;
        float pA[8], pB[8], sA = 0.0f, sB = 0.0f;
        #pragma unroll
        for (int ib = 0; ib < 8; ++ib) {
            const int k = lane + 64 * ib;
            const int kp = (N_ - k) & (N_ - 1);
            const float2 X1 = zw[PD(k)];
            const float2 X2 = zw[PD(kp)];
            pA[ib] = __expf(SCALE_ * 0.5f * (X1.x + X2.x) - mA);
            pB[ib] = __expf(SCALE_ * 0.5f * (X1.y + X2.y) - mB);
            sA += pA[ib]; sB += pB[ib];
        }
        float pAN = 0.0f, pBN = 0.0f;
        if (lane == 0) {
            const float2 XN = zw[PD(512)];
            pAN = __expf(SCALE_ * XN.x - mA);
            pBN = __expf(SCALE_ * XN.y - mB);
            sA += pAN; sB += pBN;
        }
        #pragma unroll
        for (int off = 32; off > 0; off >>= 1) {
            sA += __shfl_xor(sA, off);
            sB += __shfl_xor(sB, off);
        }
        const float iA = 1.0f / sA, iB = 1.0f / sB;
        #pragma unroll
        for (int ib = 0; ib < 8; ++ib) gacc[ib] += pA[ib] * iA + pB[ib] * iB;
        if (lane == 0) gN += pAN * iA + pBN * iB;
    }

    // merge 4 waves' register accumulators via LDS float atomics
    #pragma unroll
    for (int ib = 0; ib < 8; ++ib) atomicAdd(&s_acc[lane + 64 * ib], gacc[ib]);
    if (lane == 0) atomicAdd(&s_acc[512], gN);
    __syncthreads();

    float* Gp = G + (size_t)bh * NF_;
    for (int kk = t; kk < NF_; kk += 256) atomicAdd(&Gp[kk], s_acc[kk]);
}

// Kernel 2: block = one (b,h) x 8 e-channels (4 pairs, one per wave).
// softmax(G)->s_A computed in-block (folds old k_softA); then per wave:
// load V pair at dr4 slots, wave-private fwd FFT, IN-PLACE Hermitian*A
// manipulation (lane owns the (k,1024-k) pair), wave-private inverse FFT,
// write out. Zero barriers after the init sync.
__global__ __launch_bounds__(256) void k_vfft(const float* __restrict__ V,
                                              const float* __restrict__ G,
                                              float* __restrict__ Out) {
    __shared__ float2 s_zv[4 * ZP_];
    __shared__ float2 s_tw[ZP_];
    __shared__ float s_A[NF_];
    __shared__ float s_red[8];

    const int t = threadIdx.x;
    const int bid = blockIdx.x;
    const int bh = bid >> 3, pg = bid & 7;
    const int b = bh >> 3, h = bh & 7;
    const int w = t >> 6, lane = t & 63;
    const int e0 = 2 * (pg * 4 + w);

    fill_tw(s_tw, t);

    // ---- softmax(G[bh]) -> s_A (block-cooperative) ----
    {
        const float* Gp = G + (size_t)bh * NF_;
        const float g0 = Gp[t];
        const float g1 = Gp[t + 256];
        const float g2 = (t == 0) ? Gp[512] : -1e30f;
        float m = fmaxf(fmaxf(g0, g1), g2);
        #pragma unroll
        for (int off = 32; off > 0; off >>= 1) m = fmaxf(m, __shfl_xor(m, off));
        if (lane == 0) s_red[w] = m;
        __syncthreads();
        m = fmaxf(fmaxf(s_red[0], s_red[1]), fmaxf(s_red[2], s_red[3]));
        const float p0 = __expf(g0 - m), p1 = __expf(g1 - m);
        const float p2 = (t == 0) ? __expf(g2 - m) : 0.0f;
        float s = p0 + p1 + p2;
        #pragma unroll
        for (int off = 32; off > 0; off >>= 1) s += __shfl_xor(s, off);
        __syncthreads();
        if (lane == 0) s_red[4 + w] = s;
        __syncthreads();
        s = s_red[4] + s_red[5] + s_red[6] + s_red[7];
        const float inv = 1.0f / s;
        s_A[t] = p0 * inv;
        s_A[t + 256] = p1 * inv;
        if (t == 0) s_A[512] = p2 * inv;
    }
    __syncthreads();   // s_A + s_tw ready; no more block barriers

    float2* z = s_zv + w * ZP_;

    #pragma unroll
    for (int jb = 0; jb < 16; ++jb) {
        const int s = lane + 64 * jb;
        const float* vp = V + (((size_t)b * L_ + s) * H_ + h) * E_ + e0;
        z[PD(dr4(s))] = make_float2(vp[0], vp[1]);
    }
    __builtin_amdgcn_wave_barrier();

    wfft_dit4(z, s_tw, lane, -1.0f);   // natural-order X

    // in-place Hermitian manipulation: lane owns (k, 1024-k)
    #pragma unroll
    for (int ib = 0; ib < 8; ++ib) {
        const int k = lane + 64 * ib;
        const int kp = (N_ - k) & (N_ - 1);
        const int ik = PD(k), ikp = PD(kp);
        const float2 X1 = z[ik];
        const float2 X2 = z[ikp];
        const float reV1 = 0.5f * (X1.x + X2.x);
        const float imV1 = 0.5f * (X1.y - X2.y);
        const float reV2 = 0.5f * (X1.y + X2.y);
        const float imV2 = 0.5f * (X2.x - X1.x);
        const float a = s_A[k];
        z[ik] = make_float2(a * reV1 - imV2, imV1 + a * reV2);
        if (kp != k)
            z[ikp] = make_float2(a * reV1 + imV2, -imV1 + a * reV2);
    }
    if (lane == 0) {
        const float2 X = z[PD(512)];
        const float a = s_A[512];
        z[PD(512)] = make_float2(a * X.x, a * X.y);
    }
    __builtin_amdgcn_wave_barrier();

    wfft_dif4(z, s_tw, lane, +1.0f);   // unnormalized inverse, digit-reversed out

    const float invN = 1.0f / (float)N_;
    #pragma unroll
    for (int jb = 0; jb < 16; ++jb) {
        const int p = lane + 64 * jb;
        const int l = dr4(p);
        const float2 r = z[PD(p)];
        const size_t o = (((size_t)b * L_ + l) * E_ + e0) * H_ + h;
        Out[o] = r.x * invN;        // e0   -> Re
        Out[o + H_] = r.y * invN;   // e0+1 -> Im
    }
}

extern "C" void kernel_launch(void* const* d_in, const int* in_sizes, int n_in,
                              void* d_out, int out_size, void* d_ws, size_t ws_size,
                              hipStream_t stream) {
    const float* Q = (const float*)d_in[0];
    const float* K = (const float*)d_in[1];
    const float* V = (const float*)d_in[2];
    float* out = (float*)d_out;

    float* ws = (float*)d_ws;
    float* G     = ws;                                  // B*H*NF floats (65664 B, 16-aligned)
    _Float16* Kh = (_Float16*)(ws + B_ * H_ * NF_);     // B*L*H*E halves (4 MB)

    hipMemsetAsync(G, 0, (size_t)B_ * H_ * NF_ * sizeof(float), stream);
    k_prep<<<(B_ * L_ * H_ + 255) / 256, 256, 0, stream>>>(K, Kh);
    k_qkfft<<<B_ * H_ * (L_ / 16), 256, 0, stream>>>(Q, Kh, G);
    k_vfft<<<B_ * H_ * (E_ / 8), 256, 0, stream>>>(V, G, out);
}

// Round 11
// 123.743 us; speedup vs baseline: 1.1021x; 1.1021x over previous
//
#include <hip/hip_runtime.h>
#include <hip/hip_bf16.h>
#include <math.h>

#define B_ 4
#define L_ 1024
#define H_ 8
#define E_ 64
#define N_ 1024
#define NF_ 513            // rfft bins for N=1024
#define SCALE_ 0.125f      // 1/sqrt(E)
#define HE_ (H_ * E_)
#define ZP_ 1104           // padded float2 slots for 1024 points (PD(1023)=1101)

typedef _Float16 f16x8 __attribute__((ext_vector_type(8)));
typedef float f32x4 __attribute__((ext_vector_type(4)));

// base-4 digit reversal of a 10-bit index (5 digits); involution.
__device__ __forceinline__ int dr4(int x) {
    const int r = (int)(__brev((unsigned)x) >> 22);   // bit-reverse 10 bits
    return ((r & 0x155) << 1) | ((r >> 1) & 0x155);   // swap adjacent bits
}

// Padded LDS index: kills power-of-2 stride bank conflicts (<=2-way, free).
__device__ __forceinline__ int PD(int i) { return i + (i >> 4) + (i >> 6); }

// w = (cos, sin); multiply v by exp(dir*i*theta).
__device__ __forceinline__ float2 cmulw(float2 v, float2 w, float dir) {
    const float wi = dir * w.y;
    return make_float2(v.x * w.x - v.y * wi, v.x * wi + v.y * w.x);
}

// radix-4 combine: y_q = sum_m x_m * W4^{q*m}, W4 = exp(dir*i*pi/2).
__device__ __forceinline__ void r4c(const float2 x0, const float2 x1,
                                    const float2 x2, const float2 x3,
                                    const float dir,
                                    float2& y0, float2& y1, float2& y2, float2& y3) {
    const float ax = x0.x + x2.x, ay = x0.y + x2.y;
    const float bx = x0.x - x2.x, by = x0.y - x2.y;
    const float cx = x1.x + x3.x, cy = x1.y + x3.y;
    const float dx = x1.x - x3.x, dy = x1.y - x3.y;
    y0 = make_float2(ax + cx, ay + cy);
    y2 = make_float2(ax - cx, ay - cy);
    y1 = make_float2(bx - dir * dy, by + dir * dx);
    y3 = make_float2(bx + dir * dy, by - dir * dx);
}

// Twiddle table at padded slots: tw[PD(k)] = (cos, sin)(2*pi*k/1024).
__device__ __forceinline__ void fill_tw(float2* tw, int t) {
    for (int i = t; i < 1024; i += 256) {
        float sv, cv;
        sincosf(6.283185307179586f * (float)i / 1024.0f, &sv, &cv);
        tw[PD(i)] = make_float2(cv, sv);
    }
}

// ---- Wave-private radix-4 FFT (used in k_vfft only), no s_barrier ----
__device__ __forceinline__ void wfft_dit4(float2* z, const float2* tw, int lane, float dir) {
    #pragma unroll
    for (int st = 0; st < 5; ++st) {
        const int l2q = 2 * st, qs = 1 << l2q;
        const int step = 1 << (8 - l2q);
        #pragma unroll
        for (int ib = 0; ib < 4; ++ib) {
            const int j = lane + 64 * ib;
            const int pos = j & (qs - 1);
            const int base = ((j >> l2q) << (l2q + 2)) + pos;
            const int i0 = PD(base), i1 = PD(base + qs), i2 = PD(base + 2 * qs), i3 = PD(base + 3 * qs);
            float2 x0 = z[i0], x1 = z[i1], x2 = z[i2], x3 = z[i3];
            if (st) {
                x1 = cmulw(x1, tw[PD(pos * step)], dir);
                x2 = cmulw(x2, tw[PD(2 * pos * step)], dir);
                x3 = cmulw(x3, tw[PD(3 * pos * step)], dir);
            }
            float2 y0, y1, y2, y3;
            r4c(x0, x1, x2, x3, dir, y0, y1, y2, y3);
            z[i0] = y0; z[i1] = y1; z[i2] = y2; z[i3] = y3;
        }
        __builtin_amdgcn_wave_barrier();
    }
}

__device__ __forceinline__ void wfft_dif4(float2* z, const float2* tw, int lane, float dir) {
    #pragma unroll
    for (int st = 4; st >= 0; --st) {
        const int l2q = 2 * st, qs = 1 << l2q;
        const int step = 1 << (8 - l2q);
        #pragma unroll
        for (int ib = 0; ib < 4; ++ib) {
            const int j = lane + 64 * ib;
            const int pos = j & (qs - 1);
            const int base = ((j >> l2q) << (l2q + 2)) + pos;
            const int i0 = PD(base), i1 = PD(base + qs), i2 = PD(base + 2 * qs), i3 = PD(base + 3 * qs);
            const float2 x0 = z[i0], x1 = z[i1], x2 = z[i2], x3 = z[i3];
            float2 s0, s1, s2, s3;
            r4c(x0, x1, x2, x3, dir, s0, s1, s2, s3);
            if (st) {
                s1 = cmulw(s1, tw[PD(pos * step)], dir);
                s2 = cmulw(s2, tw[PD(2 * pos * step)], dir);
                s3 = cmulw(s3, tw[PD(3 * pos * step)], dir);
            }
            z[i0] = s0; z[i1] = s1; z[i2] = s2; z[i3] = s3;
        }
        __builtin_amdgcn_wave_barrier();
    }
}

// Kernel 0: K rows -> unit-normalized f16 (Kh).
__global__ __launch_bounds__(256) void k_prep(const float* __restrict__ K,
                                              _Float16* __restrict__ Kh) {
    const int i = blockIdx.x * 256 + threadIdx.x;
    if (i >= B_ * L_ * H_) return;
    const float* p = K + (size_t)i * E_;
    float ss = 0.0f;
    #pragma unroll
    for (int j = 0; j < 16; ++j) {
        const float4 v = *(const float4*)(p + j * 4);
        ss += v.x * v.x + v.y * v.y + v.z * v.z + v.w * v.w;
    }
    const float r = rsqrtf(ss);
    _Float16* out = Kh + (size_t)i * E_;
    #pragma unroll
    for (int e = 0; e < E_; e += 8) {
        const float4 x = *(const float4*)(p + e);
        const float4 y = *(const float4*)(p + e + 4);
        f16x8 o;
        o[0] = (_Float16)(x.x * r); o[1] = (_Float16)(x.y * r);
        o[2] = (_Float16)(x.z * r); o[3] = (_Float16)(x.w * r);
        o[4] = (_Float16)(y.x * r); o[5] = (_Float16)(y.y * r);
        o[6] = (_Float16)(y.z * r); o[7] = (_Float16)(y.w * r);
        *(f16x8*)(out + e) = o;
    }
}

// Kernel 1: block = one (b,h) x 16 q-rows. MFMA QK^T (slot j <- K row dr4(j)),
// then 4 rounds x {scatter 4 rows into TWO padded buffers, block-cooperative
// dual radix-4 DIT (addressing amortized across both buffers), DC-max softmax
// (exact row max), s_acc accumulate}. 2-buffer geometry: LDS ~28.7 KB ->
// 5 blocks/CU by LDS (round 9's 4-buffer/46.6KB capped at 3; kernel is
// latency-bound so cross-block TLP at barriers is the scarce resource).
// Round-10 lesson: wave-private FFT recomputes per-point addresses (4x VALU)
// and regressed; block-cooperative + amortized addressing wins.
__global__ __attribute__((amdgpu_flat_work_group_size(256, 256), amdgpu_waves_per_eu(2, 5)))
void k_qkfft(const float* __restrict__ Q,
             const _Float16* __restrict__ Kh,
             float* __restrict__ G) {
    __shared__ float2 s_z[2 * ZP_];   // 2 padded FFT buffers (17.7 KB)
    __shared__ float2 s_tw[ZP_];      // padded twiddles (8.8 KB)
    __shared__ float s_acc[NF_];
    __shared__ float s_red[16];

    const int t = threadIdx.x;
    const int bid = blockIdx.x;
    const int bh = bid >> 6;        // consecutive blocks share (b,h) -> L2 reuse of Kh
    const int chunk = bid & 63;
    const int b = bh >> 3, h = bh & 7;
    const int l0 = chunk * 16;

    const int c = t & 15;           // A-row / B-col within 16-tile
    const int g = (t >> 4) & 3;     // k-group of the fragment / acc row-group
    const int w = t >> 6;           // wave id
    const int lane = t & 63, wid = w;

    fill_tw(s_tw, t);
    for (int kk = t; kk < NF_; kk += 256) s_acc[kk] = 0.0f;

    // ---- A fragments: q-row (l0+c); norm inline (2 shuffles) ----
    const float* qrow = Q + (((size_t)b * L_ + l0 + c) * H_ + h) * E_;
    const float4 x0 = *(const float4*)(qrow + g * 8);
    const float4 y0 = *(const float4*)(qrow + g * 8 + 4);
    const float4 x1 = *(const float4*)(qrow + 32 + g * 8);
    const float4 y1 = *(const float4*)(qrow + 32 + g * 8 + 4);
    float ss = x0.x * x0.x + x0.y * x0.y + x0.z * x0.z + x0.w * x0.w
             + y0.x * y0.x + y0.y * y0.y + y0.z * y0.z + y0.w * y0.w
             + x1.x * x1.x + x1.y * x1.y + x1.z * x1.z + x1.w * x1.w
             + y1.x * y1.x + y1.y * y1.y + y1.z * y1.z + y1.w * y1.w;
    ss += __shfl_xor(ss, 16);
    ss += __shfl_xor(ss, 32);       // lanes {c, c+16, c+32, c+48} share a row
    const float qn = rsqrtf(ss);
    f16x8 af0, af1;
    af0[0] = (_Float16)(x0.x * qn); af0[1] = (_Float16)(x0.y * qn);
    af0[2] = (_Float16)(x0.z * qn); af0[3] = (_Float16)(x0.w * qn);
    af0[4] = (_Float16)(y0.x * qn); af0[5] = (_Float16)(y0.y * qn);
    af0[6] = (_Float16)(y0.z * qn); af0[7] = (_Float16)(y0.w * qn);
    af1[0] = (_Float16)(x1.x * qn); af1[1] = (_Float16)(x1.y * qn);
    af1[2] = (_Float16)(x1.z * qn); af1[3] = (_Float16)(x1.w * qn);
    af1[4] = (_Float16)(y1.x * qn); af1[5] = (_Float16)(y1.y * qn);
    af1[6] = (_Float16)(y1.z * qn); af1[7] = (_Float16)(y1.w * qn);

    // ---- B fragments + MFMA: 16 N-tiles, 2 k-steps each ----
    f32x4 acc[16];
    #pragma unroll
    for (int n = 0; n < 16; ++n) acc[n] = (f32x4){0.0f, 0.0f, 0.0f, 0.0f};

    #pragma unroll
    for (int n = 0; n < 16; ++n) {
        const int j = w * 256 + n * 16 + c;
        const int s = dr4(j);
        const f16x8* bp = (const f16x8*)(Kh + (((size_t)b * L_ + s) * H_ + h) * E_);
        const f16x8 b0 = bp[g];
        const f16x8 b1 = bp[4 + g];
        acc[n] = __builtin_amdgcn_mfma_f32_16x16x32_f16(af0, b0, acc[n], 0, 0, 0);
        acc[n] = __builtin_amdgcn_mfma_f32_16x16x32_f16(af1, b1, acc[n], 0, 0, 0);
        if ((n & 3) == 3) __builtin_amdgcn_sched_barrier(0);  // fence load hoisting
    }

    // sim = exp(cos) in place
    #pragma unroll
    for (int n = 0; n < 16; ++n) {
        #pragma unroll
        for (int r = 0; r < 4; ++r) acc[n][r] = __expf(acc[n][r]);
    }

    const float dir = -1.0f;

    // ---- 4 rounds x (2 concurrent pair-FFTs + fused 4-row softmax) ----
    #pragma unroll 1
    for (int rr = 0; rr < 4; ++rr) {
        __syncthreads();   // buffers free (prev round reads / rr=0 init done)
        if (g == rr) {     // rows 4rr..4rr+3: regs 0,1 -> buf0; regs 2,3 -> buf1
            #pragma unroll
            for (int n = 0; n < 16; ++n) {
                const int ps = PD(w * 256 + n * 16 + c);
                s_z[ps]       = make_float2(acc[n][0], acc[n][1]);
                s_z[ZP_ + ps] = make_float2(acc[n][2], acc[n][3]);
            }
        }
        __syncthreads();   // scatter visible

        // dual radix-4 DIT (digit-reversed in -> natural out), 5 barriers
        #pragma unroll
        for (int st = 0; st < 5; ++st) {
            const int l2q = 2 * st, qs = 1 << l2q;
            const int pos = t & (qs - 1);
            const int base = ((t >> l2q) << (l2q + 2)) + pos;
            const int i0 = PD(base), i1 = PD(base + qs), i2 = PD(base + 2 * qs), i3 = PD(base + 3 * qs);
            float2 w1, w2, w3;
            if (st) {
                const int step = 1 << (8 - l2q);
                w1 = s_tw[PD(pos * step)];
                w2 = s_tw[PD(2 * pos * step)];
                w3 = s_tw[PD(3 * pos * step)];
            }
            #pragma unroll
            for (int q = 0; q < 2; ++q) {
                float2* z = s_z + q * ZP_;
                float2 a0 = z[i0], a1 = z[i1], a2 = z[i2], a3 = z[i3];
                if (st) { a1 = cmulw(a1, w1, dir); a2 = cmulw(a2, w2, dir); a3 = cmulw(a3, w3, dir); }
                float2 b0, b1, b2, b3;
                r4c(a0, a1, a2, a3, dir, b0, b1, b2, b3);
                z[i0] = b0; z[i1] = b1; z[i2] = b2; z[i3] = b3;
            }
            __syncthreads();
        }

        // extraction: 4 rows; softmax max = DC bin (exact), no max reduce
        const int iT = PD(t), iTn = PD((N_ - t) & (N_ - 1));
        const int iU = PD(t + 256), iUn = PD(768 - t);
        float p[4][2], pm[4], sm[4];
        #pragma unroll
        for (int q = 0; q < 2; ++q) {
            const float2* z = s_z + q * ZP_;
            const float2 X0 = z[iT], X0n = z[iTn], X1 = z[iU], X1n = z[iUn];
            const float2 DC = z[0];                 // PD(0)==0, broadcast
            const float2 XN = z[PD(512)];           // Nyquist bin (used @t0)
            const float mA = SCALE_ * DC.x, mB = SCALE_ * DC.y;
            p[2 * q][0]     = __expf(SCALE_ * 0.5f * (X0.x + X0n.x) - mA);
            p[2 * q][1]     = __expf(SCALE_ * 0.5f * (X1.x + X1n.x) - mA);
            p[2 * q + 1][0] = __expf(SCALE_ * 0.5f * (X0.y + X0n.y) - mB);
            p[2 * q + 1][1] = __expf(SCALE_ * 0.5f * (X1.y + X1n.y) - mB);
            pm[2 * q]     = __expf(SCALE_ * XN.x - mA);
            pm[2 * q + 1] = __expf(SCALE_ * XN.y - mB);
            sm[2 * q]     = p[2 * q][0] + p[2 * q][1] + ((t == 0) ? pm[2 * q] : 0.0f);
            sm[2 * q + 1] = p[2 * q + 1][0] + p[2 * q + 1][1] + ((t == 0) ? pm[2 * q + 1] : 0.0f);
        }
        #pragma unroll
        for (int off = 32; off > 0; off >>= 1) {
            #pragma unroll
            for (int q2 = 0; q2 < 4; ++q2) sm[q2] += __shfl_xor(sm[q2], off);
        }
        if (lane == 0) {
            #pragma unroll
            for (int q2 = 0; q2 < 4; ++q2) s_red[4 * q2 + wid] = sm[q2];
        }
        __syncthreads();
        float add0 = 0.0f, add1 = 0.0f, addm = 0.0f;
        #pragma unroll
        for (int q2 = 0; q2 < 4; ++q2) {
            const float inv = 1.0f / (s_red[4 * q2] + s_red[4 * q2 + 1] +
                                      s_red[4 * q2 + 2] + s_red[4 * q2 + 3]);
            add0 += p[q2][0] * inv;
            add1 += p[q2][1] * inv;
            addm += pm[q2] * inv;
        }
        s_acc[t]       += add0;
        s_acc[t + 256] += add1;
        if (t == 0) s_acc[512] += addm;
    }
    __syncthreads();

    float* Gp = G + (size_t)bh * NF_;
    for (int kk = t; kk < NF_; kk += 256) atomicAdd(&Gp[kk], s_acc[kk]);
}

// Kernel 2: block = one (b,h) x 8 e-channels (4 pairs, one per wave).
// softmax(G)->s_A in-block; per wave: V pair at dr4 slots, wave-private fwd
// FFT, in-place Hermitian*A manipulation, wave-private inverse FFT, write.
__global__ __launch_bounds__(256) void k_vfft(const float* __restrict__ V,
                                              const float* __restrict__ G,
                                              float* __restrict__ Out) {
    __shared__ float2 s_zv[4 * ZP_];
    __shared__ float2 s_tw[ZP_];
    __shared__ float s_A[NF_];
    __shared__ float s_red[8];

    const int t = threadIdx.x;
    const int bid = blockIdx.x;
    const int bh = bid >> 3, pg = bid & 7;
    const int b = bh >> 3, h = bh & 7;
    const int w = t >> 6, lane = t & 63;
    const int e0 = 2 * (pg * 4 + w);

    fill_tw(s_tw, t);

    // ---- softmax(G[bh]) -> s_A (block-cooperative) ----
    {
        const float* Gp = G + (size_t)bh * NF_;
        const float g0 = Gp[t];
        const float g1 = Gp[t + 256];
        const float g2 = (t == 0) ? Gp[512] : -1e30f;
        float m = fmaxf(fmaxf(g0, g1), g2);
        #pragma unroll
        for (int off = 32; off > 0; off >>= 1) m = fmaxf(m, __shfl_xor(m, off));
        if (lane == 0) s_red[w] = m;
        __syncthreads();
        m = fmaxf(fmaxf(s_red[0], s_red[1]), fmaxf(s_red[2], s_red[3]));
        const float p0 = __expf(g0 - m), p1 = __expf(g1 - m);
        const float p2 = (t == 0) ? __expf(g2 - m) : 0.0f;
        float s = p0 + p1 + p2;
        #pragma unroll
        for (int off = 32; off > 0; off >>= 1) s += __shfl_xor(s, off);
        __syncthreads();
        if (lane == 0) s_red[4 + w] = s;
        __syncthreads();
        s = s_red[4] + s_red[5] + s_red[6] + s_red[7];
        const float inv = 1.0f / s;
        s_A[t] = p0 * inv;
        s_A[t + 256] = p1 * inv;
        if (t == 0) s_A[512] = p2 * inv;
    }
    __syncthreads();   // s_A + s_tw ready; no more block barriers

    float2* z = s_zv + w * ZP_;

    #pragma unroll
    for (int jb = 0; jb < 16; ++jb) {
        const int s = lane + 64 * jb;
        const float* vp = V + (((size_t)b * L_ + s) * H_ + h) * E_ + e0;
        z[PD(dr4(s))] = make_float2(vp[0], vp[1]);
    }
    __builtin_amdgcn_wave_barrier();

    wfft_dit4(z, s_tw, lane, -1.0f);   // natural-order X

    // in-place Hermitian manipulation: lane owns (k, 1024-k)
    #pragma unroll
    for (int ib = 0; ib < 8; ++ib) {
        const int k = lane + 64 * ib;
        const int kp = (N_ - k) & (N_ - 1);
        const int ik = PD(k), ikp = PD(kp);
        const float2 X1 = z[ik];
        const float2 X2 = z[ikp];
        const float reV1 = 0.5f * (X1.x + X2.x);
        const float imV1 = 0.5f * (X1.y - X2.y);
        const float reV2 = 0.5f * (X1.y + X2.y);
        const float imV2 = 0.5f * (X2.x - X1.x);
        const float a = s_A[k];
        z[ik] = make_float2(a * reV1 - imV2, imV1 + a * reV2);
        if (kp != k)
            z[ikp] = make_float2(a * reV1 + imV2, -imV1 + a * reV2);
    }
    if (lane == 0) {
        const float2 X = z[PD(512)];
        const float a = s_A[512];
        z[PD(512)] = make_float2(a * X.x, a * X.y);
    }
    __builtin_amdgcn_wave_barrier();

    wfft_dif4(z, s_tw, lane, +1.0f);   // unnormalized inverse, digit-reversed out

    const float invN = 1.0f / (float)N_;
    #pragma unroll
    for (int jb = 0; jb < 16; ++jb) {
        const int p = lane + 64 * jb;
        const int l = dr4(p);
        const float2 r = z[PD(p)];
        const size_t o = (((size_t)b * L_ + l) * E_ + e0) * H_ + h;
        Out[o] = r.x * invN;        // e0   -> Re
        Out[o + H_] = r.y * invN;   // e0+1 -> Im
    }
}

extern "C" void kernel_launch(void* const* d_in, const int* in_sizes, int n_in,
                              void* d_out, int out_size, void* d_ws, size_t ws_size,
                              hipStream_t stream) {
    const float* Q = (const float*)d_in[0];
    const float* K = (const float*)d_in[1];
    const float* V = (const float*)d_in[2];
    float* out = (float*)d_out;

    float* ws = (float*)d_ws;
    float* G     = ws;                                  // B*H*NF floats
    _Float16* Kh = (_Float16*)(ws + B_ * H_ * NF_);     // B*L*H*E halves (4 MB)

    hipMemsetAsync(G, 0, (size_t)B_ * H_ * NF_ * sizeof(float), stream);
    k_prep<<<(B_ * L_ * H_ + 255) / 256, 256, 0, stream>>>(K, Kh);
    k_qkfft<<<B_ * H_ * (L_ / 16), 256, 0, stream>>>(Q, Kh, G);
    k_vfft<<<B_ * H_ * (E_ / 8), 256, 0, stream>>>(V, G, out);
}

// Round 12
// 117.777 us; speedup vs baseline: 1.1580x; 1.0507x over previous
//
#include <hip/hip_runtime.h>
#include <hip/hip_bf16.h>
#include <math.h>

#define B_ 4
#define L_ 1024
#define H_ 8
#define E_ 64
#define N_ 1024
#define NF_ 513            // rfft bins for N=1024
#define SCALE_ 0.125f      // 1/sqrt(E)
#define HE_ (H_ * E_)
#define ZP_ 1104           // padded float2 slots for 1024 points (PD(1023)=1101)

typedef _Float16 f16x8 __attribute__((ext_vector_type(8)));
typedef float f32x4 __attribute__((ext_vector_type(4)));

// base-4 digit reversal of a 10-bit index (5 digits); involution.
__device__ __forceinline__ int dr4(int x) {
    const int r = (int)(__brev((unsigned)x) >> 22);   // bit-reverse 10 bits
    return ((r & 0x155) << 1) | ((r >> 1) & 0x155);   // swap adjacent bits
}

// Padded LDS index: kills power-of-2 STRIDED bank conflicts (<=2-way, free).
// NOTE: does NOT fix stage-0's consecutive-quad pattern -- that needs the
// butterfly->thread permutation (see sigma in the FFT stage loops).
__device__ __forceinline__ int PD(int i) { return i + (i >> 4) + (i >> 6); }

// w = (cos, sin); multiply v by exp(dir*i*theta).
__device__ __forceinline__ float2 cmulw(float2 v, float2 w, float dir) {
    const float wi = dir * w.y;
    return make_float2(v.x * w.x - v.y * wi, v.x * wi + v.y * w.x);
}

// radix-4 combine: y_q = sum_m x_m * W4^{q*m}, W4 = exp(dir*i*pi/2).
__device__ __forceinline__ void r4c(const float2 x0, const float2 x1,
                                    const float2 x2, const float2 x3,
                                    const float dir,
                                    float2& y0, float2& y1, float2& y2, float2& y3) {
    const float ax = x0.x + x2.x, ay = x0.y + x2.y;
    const float bx = x0.x - x2.x, by = x0.y - x2.y;
    const float cx = x1.x + x3.x, cy = x1.y + x3.y;
    const float dx = x1.x - x3.x, dy = x1.y - x3.y;
    y0 = make_float2(ax + cx, ay + cy);
    y2 = make_float2(ax - cx, ay - cy);
    y1 = make_float2(bx - dir * dy, by + dir * dx);
    y3 = make_float2(bx + dir * dy, by - dir * dx);
}

// Twiddle table at padded slots: tw[PD(k)] = (cos, sin)(2*pi*k/1024).
__device__ __forceinline__ void fill_tw(float2* tw, int t) {
    for (int i = t; i < 1024; i += 256) {
        float sv, cv;
        sincosf(6.283185307179586f * (float)i / 1024.0f, &sv, &cv);
        tw[PD(i)] = make_float2(cv, sv);
    }
}

// ---- Wave-private radix-4 FFT (k_vfft), no s_barrier ----
// Stage 0 uses permuted butterfly assignment: lane l -> butterfly
// 4*(l&15) + (l>>4) (+64*ib), making addresses stride-16 (conflict-optimal)
// instead of consecutive quads (16-way conflict).
__device__ __forceinline__ void wfft_dit4(float2* z, const float2* tw, int lane, float dir) {
    #pragma unroll
    for (int st = 0; st < 5; ++st) {
        const int l2q = 2 * st, qs = 1 << l2q;
        const int step = 1 << (8 - l2q);
        #pragma unroll
        for (int ib = 0; ib < 4; ++ib) {
            const int j = (st == 0) ? (((lane & 15) << 2) | (lane >> 4)) + 64 * ib
                                    : lane + 64 * ib;
            const int pos = j & (qs - 1);
            const int base = ((j >> l2q) << (l2q + 2)) + pos;
            const int i0 = PD(base), i1 = PD(base + qs), i2 = PD(base + 2 * qs), i3 = PD(base + 3 * qs);
            float2 x0 = z[i0], x1 = z[i1], x2 = z[i2], x3 = z[i3];
            if (st) {
                x1 = cmulw(x1, tw[PD(pos * step)], dir);
                x2 = cmulw(x2, tw[PD(2 * pos * step)], dir);
                x3 = cmulw(x3, tw[PD(3 * pos * step)], dir);
            }
            float2 y0, y1, y2, y3;
            r4c(x0, x1, x2, x3, dir, y0, y1, y2, y3);
            z[i0] = y0; z[i1] = y1; z[i2] = y2; z[i3] = y3;
        }
        __builtin_amdgcn_wave_barrier();
    }
}

__device__ __forceinline__ void wfft_dif4(float2* z, const float2* tw, int lane, float dir) {
    #pragma unroll
    for (int st = 4; st >= 0; --st) {
        const int l2q = 2 * st, qs = 1 << l2q;
        const int step = 1 << (8 - l2q);
        #pragma unroll
        for (int ib = 0; ib < 4; ++ib) {
            const int j = (st == 0) ? (((lane & 15) << 2) | (lane >> 4)) + 64 * ib
                                    : lane + 64 * ib;
            const int pos = j & (qs - 1);
            const int base = ((j >> l2q) << (l2q + 2)) + pos;
            const int i0 = PD(base), i1 = PD(base + qs), i2 = PD(base + 2 * qs), i3 = PD(base + 3 * qs);
            const float2 x0 = z[i0], x1 = z[i1], x2 = z[i2], x3 = z[i3];
            float2 s0, s1, s2, s3;
            r4c(x0, x1, x2, x3, dir, s0, s1, s2, s3);
            if (st) {
                s1 = cmulw(s1, tw[PD(pos * step)], dir);
                s2 = cmulw(s2, tw[PD(2 * pos * step)], dir);
                s3 = cmulw(s3, tw[PD(3 * pos * step)], dir);
            }
            z[i0] = s0; z[i1] = s1; z[i2] = s2; z[i3] = s3;
        }
        __builtin_amdgcn_wave_barrier();
    }
}

// Kernel 0: K rows -> unit-normalized f16 (Kh).
__global__ __launch_bounds__(256) void k_prep(const float* __restrict__ K,
                                              _Float16* __restrict__ Kh) {
    const int i = blockIdx.x * 256 + threadIdx.x;
    if (i >= B_ * L_ * H_) return;
    const float* p = K + (size_t)i * E_;
    float ss = 0.0f;
    #pragma unroll
    for (int j = 0; j < 16; ++j) {
        const float4 v = *(const float4*)(p + j * 4);
        ss += v.x * v.x + v.y * v.y + v.z * v.z + v.w * v.w;
    }
    const float r = rsqrtf(ss);
    _Float16* out = Kh + (size_t)i * E_;
    #pragma unroll
    for (int e = 0; e < E_; e += 8) {
        const float4 x = *(const float4*)(p + e);
        const float4 y = *(const float4*)(p + e + 4);
        f16x8 o;
        o[0] = (_Float16)(x.x * r); o[1] = (_Float16)(x.y * r);
        o[2] = (_Float16)(x.z * r); o[3] = (_Float16)(x.w * r);
        o[4] = (_Float16)(y.x * r); o[5] = (_Float16)(y.y * r);
        o[6] = (_Float16)(y.z * r); o[7] = (_Float16)(y.w * r);
        *(f16x8*)(out + e) = o;
    }
}

// Kernel 1: block = one (b,h) x 16 q-rows. MFMA QK^T (slot j <- K row dr4(j)),
// then 2 rounds x {scatter 8 rows into FOUR padded buffers, block-cooperative
// quad radix-4 DIT (addressing amortized 4x), DC-max softmax (exact row max),
// s_acc accumulate}. Round-9 geometry (best measured: 81us) + stage-0
// butterfly permutation (kills the remaining ~9e6 bank-conflict cycles).
__global__ __attribute__((amdgpu_flat_work_group_size(256, 256), amdgpu_waves_per_eu(2, 3)))
void k_qkfft(const float* __restrict__ Q,
             const _Float16* __restrict__ Kh,
             float* __restrict__ G) {
    __shared__ float2 s_z[4 * ZP_];   // 4 padded FFT buffers (35.3 KB)
    __shared__ float2 s_tw[ZP_];      // padded twiddles (8.8 KB)
    __shared__ float s_acc[NF_];
    __shared__ float s_red[32];

    const int t = threadIdx.x;
    const int bid = blockIdx.x;
    const int bh = bid >> 6;        // consecutive blocks share (b,h) -> L2 reuse of Kh
    const int chunk = bid & 63;
    const int b = bh >> 3, h = bh & 7;
    const int l0 = chunk * 16;

    const int c = t & 15;           // A-row / B-col within 16-tile
    const int g = (t >> 4) & 3;     // k-group of the fragment / acc row-group
    const int w = t >> 6;           // wave id
    const int lane = t & 63, wid = w;

    fill_tw(s_tw, t);
    for (int kk = t; kk < NF_; kk += 256) s_acc[kk] = 0.0f;

    // ---- A fragments: q-row (l0+c); norm inline (2 shuffles) ----
    const float* qrow = Q + (((size_t)b * L_ + l0 + c) * H_ + h) * E_;
    const float4 x0 = *(const float4*)(qrow + g * 8);
    const float4 y0 = *(const float4*)(qrow + g * 8 + 4);
    const float4 x1 = *(const float4*)(qrow + 32 + g * 8);
    const float4 y1 = *(const float4*)(qrow + 32 + g * 8 + 4);
    float ss = x0.x * x0.x + x0.y * x0.y + x0.z * x0.z + x0.w * x0.w
             + y0.x * y0.x + y0.y * y0.y + y0.z * y0.z + y0.w * y0.w
             + x1.x * x1.x + x1.y * x1.y + x1.z * x1.z + x1.w * x1.w
             + y1.x * y1.x + y1.y * y1.y + y1.z * y1.z + y1.w * y1.w;
    ss += __shfl_xor(ss, 16);
    ss += __shfl_xor(ss, 32);       // lanes {c, c+16, c+32, c+48} share a row
    const float qn = rsqrtf(ss);
    f16x8 af0, af1;
    af0[0] = (_Float16)(x0.x * qn); af0[1] = (_Float16)(x0.y * qn);
    af0[2] = (_Float16)(x0.z * qn); af0[3] = (_Float16)(x0.w * qn);
    af0[4] = (_Float16)(y0.x * qn); af0[5] = (_Float16)(y0.y * qn);
    af0[6] = (_Float16)(y0.z * qn); af0[7] = (_Float16)(y0.w * qn);
    af1[0] = (_Float16)(x1.x * qn); af1[1] = (_Float16)(x1.y * qn);
    af1[2] = (_Float16)(x1.z * qn); af1[3] = (_Float16)(x1.w * qn);
    af1[4] = (_Float16)(y1.x * qn); af1[5] = (_Float16)(y1.y * qn);
    af1[6] = (_Float16)(y1.z * qn); af1[7] = (_Float16)(y1.w * qn);

    // ---- B fragments + MFMA: 16 N-tiles, 2 k-steps each ----
    f32x4 acc[16];
    #pragma unroll
    for (int n = 0; n < 16; ++n) acc[n] = (f32x4){0.0f, 0.0f, 0.0f, 0.0f};

    #pragma unroll
    for (int n = 0; n < 16; ++n) {
        const int j = w * 256 + n * 16 + c;
        const int s = dr4(j);
        const f16x8* bp = (const f16x8*)(Kh + (((size_t)b * L_ + s) * H_ + h) * E_);
        const f16x8 b0 = bp[g];
        const f16x8 b1 = bp[4 + g];
        acc[n] = __builtin_amdgcn_mfma_f32_16x16x32_f16(af0, b0, acc[n], 0, 0, 0);
        acc[n] = __builtin_amdgcn_mfma_f32_16x16x32_f16(af1, b1, acc[n], 0, 0, 0);
        if ((n & 3) == 3) __builtin_amdgcn_sched_barrier(0);  // fence load hoisting
    }

    // sim = exp(cos) in place
    #pragma unroll
    for (int n = 0; n < 16; ++n) {
        #pragma unroll
        for (int r = 0; r < 4; ++r) acc[n][r] = __expf(acc[n][r]);
    }

    const float dir = -1.0f;

    // ---- 2 rounds x (4 concurrent pair-FFTs + fused 8-row softmax) ----
    #pragma unroll
    for (int rr = 0; rr < 2; ++rr) {
        __syncthreads();   // buffers free (prev round reads / init done)
        {
            const int gq = g - 2 * rr;   // rows 8rr..8rr+7 live in g = 2rr, 2rr+1
            if (gq == 0 || gq == 1) {
                float2* z01 = s_z + (2 * gq) * ZP_;
                #pragma unroll
                for (int n = 0; n < 16; ++n) {
                    const int ps = PD(w * 256 + n * 16 + c);
                    z01[ps]       = make_float2(acc[n][0], acc[n][1]);
                    z01[ZP_ + ps] = make_float2(acc[n][2], acc[n][3]);
                }
            }
        }
        __syncthreads();   // scatter visible

        // quad radix-4 DIT (digit-reversed in -> natural out), 5 barriers.
        // st=0: permuted butterfly assignment -> stride-16 addresses.
        #pragma unroll
        for (int st = 0; st < 5; ++st) {
            const int l2q = 2 * st, qs = 1 << l2q;
            const int j = (st == 0) ? (((t & 63) << 2) | (t >> 6)) : t;
            const int pos = j & (qs - 1);
            const int base = ((j >> l2q) << (l2q + 2)) + pos;
            const int i0 = PD(base), i1 = PD(base + qs), i2 = PD(base + 2 * qs), i3 = PD(base + 3 * qs);
            float2 w1, w2, w3;
            if (st) {
                const int step = 1 << (8 - l2q);
                w1 = s_tw[PD(pos * step)];
                w2 = s_tw[PD(2 * pos * step)];
                w3 = s_tw[PD(3 * pos * step)];
            }
            #pragma unroll
            for (int q = 0; q < 4; ++q) {
                float2* z = s_z + q * ZP_;
                float2 a0 = z[i0], a1 = z[i1], a2 = z[i2], a3 = z[i3];
                if (st) { a1 = cmulw(a1, w1, dir); a2 = cmulw(a2, w2, dir); a3 = cmulw(a3, w3, dir); }
                float2 b0, b1, b2, b3;
                r4c(a0, a1, a2, a3, dir, b0, b1, b2, b3);
                z[i0] = b0; z[i1] = b1; z[i2] = b2; z[i3] = b3;
            }
            __syncthreads();
        }

        // extraction: 8 rows; softmax max = DC bin (exact), no max reduce
        const int iT = PD(t), iTn = PD((N_ - t) & (N_ - 1));
        const int iU = PD(t + 256), iUn = PD(768 - t);
        float p[8][2], pm[8], sm[8];
        #pragma unroll
        for (int q = 0; q < 4; ++q) {
            const float2* z = s_z + q * ZP_;
            const float2 X0 = z[iT], X0n = z[iTn], X1 = z[iU], X1n = z[iUn];
            const float2 DC = z[0];                 // PD(0)==0, broadcast
            const float2 XN = z[PD(512)];           // Nyquist bin (used @t0)
            const float mA = SCALE_ * DC.x, mB = SCALE_ * DC.y;
            p[2 * q][0]     = __expf(SCALE_ * 0.5f * (X0.x + X0n.x) - mA);
            p[2 * q][1]     = __expf(SCALE_ * 0.5f * (X1.x + X1n.x) - mA);
            p[2 * q + 1][0] = __expf(SCALE_ * 0.5f * (X0.y + X0n.y) - mB);
            p[2 * q + 1][1] = __expf(SCALE_ * 0.5f * (X1.y + X1n.y) - mB);
            pm[2 * q]     = __expf(SCALE_ * XN.x - mA);
            pm[2 * q + 1] = __expf(SCALE_ * XN.y - mB);
            sm[2 * q]     = p[2 * q][0] + p[2 * q][1] + ((t == 0) ? pm[2 * q] : 0.0f);
            sm[2 * q + 1] = p[2 * q + 1][0] + p[2 * q + 1][1] + ((t == 0) ? pm[2 * q + 1] : 0.0f);
        }
        #pragma unroll
        for (int off = 32; off > 0; off >>= 1) {
            #pragma unroll
            for (int q2 = 0; q2 < 8; ++q2) sm[q2] += __shfl_xor(sm[q2], off);
        }
        if (lane == 0) {
            #pragma unroll
            for (int q2 = 0; q2 < 8; ++q2) s_red[4 * q2 + wid] = sm[q2];
        }
        __syncthreads();
        float add0 = 0.0f, add1 = 0.0f, addm = 0.0f;
        #pragma unroll
        for (int q2 = 0; q2 < 8; ++q2) {
            const float inv = 1.0f / (s_red[4 * q2] + s_red[4 * q2 + 1] +
                                      s_red[4 * q2 + 2] + s_red[4 * q2 + 3]);
            add0 += p[q2][0] * inv;
            add1 += p[q2][1] * inv;
            addm += pm[q2] * inv;
        }
        s_acc[t]       += add0;
        s_acc[t + 256] += add1;
        if (t == 0) s_acc[512] += addm;
    }
    __syncthreads();

    float* Gp = G + (size_t)bh * NF_;
    for (int kk = t; kk < NF_; kk += 256) atomicAdd(&Gp[kk], s_acc[kk]);
}

// Kernel 2: block = one (b,h) x 8 e-channels (4 pairs, one per wave).
// softmax(G)->s_A in-block; per wave: V pair at dr4 slots, wave-private fwd
// FFT, in-place Hermitian*A manipulation, wave-private inverse FFT, write.
__global__ __launch_bounds__(256) void k_vfft(const float* __restrict__ V,
                                              const float* __restrict__ G,
                                              float* __restrict__ Out) {
    __shared__ float2 s_zv[4 * ZP_];
    __shared__ float2 s_tw[ZP_];
    __shared__ float s_A[NF_];
    __shared__ float s_red[8];

    const int t = threadIdx.x;
    const int bid = blockIdx.x;
    const int bh = bid >> 3, pg = bid & 7;
    const int b = bh >> 3, h = bh & 7;
    const int w = t >> 6, lane = t & 63;
    const int e0 = 2 * (pg * 4 + w);

    fill_tw(s_tw, t);

    // ---- softmax(G[bh]) -> s_A (block-cooperative) ----
    {
        const float* Gp = G + (size_t)bh * NF_;
        const float g0 = Gp[t];
        const float g1 = Gp[t + 256];
        const float g2 = (t == 0) ? Gp[512] : -1e30f;
        float m = fmaxf(fmaxf(g0, g1), g2);
        #pragma unroll
        for (int off = 32; off > 0; off >>= 1) m = fmaxf(m, __shfl_xor(m, off));
        if (lane == 0) s_red[w] = m;
        __syncthreads();
        m = fmaxf(fmaxf(s_red[0], s_red[1]), fmaxf(s_red[2], s_red[3]));
        const float p0 = __expf(g0 - m), p1 = __expf(g1 - m);
        const float p2 = (t == 0) ? __expf(g2 - m) : 0.0f;
        float s = p0 + p1 + p2;
        #pragma unroll
        for (int off = 32; off > 0; off >>= 1) s += __shfl_xor(s, off);
        __syncthreads();
        if (lane == 0) s_red[4 + w] = s;
        __syncthreads();
        s = s_red[4] + s_red[5] + s_red[6] + s_red[7];
        const float inv = 1.0f / s;
        s_A[t] = p0 * inv;
        s_A[t + 256] = p1 * inv;
        if (t == 0) s_A[512] = p2 * inv;
    }
    __syncthreads();   // s_A + s_tw ready; no more block barriers

    float2* z = s_zv + w * ZP_;

    #pragma unroll
    for (int jb = 0; jb < 16; ++jb) {
        const int s = lane + 64 * jb;
        const float* vp = V + (((size_t)b * L_ + s) * H_ + h) * E_ + e0;
        z[PD(dr4(s))] = make_float2(vp[0], vp[1]);
    }
    __builtin_amdgcn_wave_barrier();

    wfft_dit4(z, s_tw, lane, -1.0f);   // natural-order X

    // in-place Hermitian manipulation: lane owns (k, 1024-k)
    #pragma unroll
    for (int ib = 0; ib < 8; ++ib) {
        const int k = lane + 64 * ib;
        const int kp = (N_ - k) & (N_ - 1);
        const int ik = PD(k), ikp = PD(kp);
        const float2 X1 = z[ik];
        const float2 X2 = z[ikp];
        const float reV1 = 0.5f * (X1.x + X2.x);
        const float imV1 = 0.5f * (X1.y - X2.y);
        const float reV2 = 0.5f * (X1.y + X2.y);
        const float imV2 = 0.5f * (X2.x - X1.x);
        const float a = s_A[k];
        z[ik] = make_float2(a * reV1 - imV2, imV1 + a * reV2);
        if (kp != k)
            z[ikp] = make_float2(a * reV1 + imV2, -imV1 + a * reV2);
    }
    if (lane == 0) {
        const float2 X = z[PD(512)];
        const float a = s_A[512];
        z[PD(512)] = make_float2(a * X.x, a * X.y);
    }
    __builtin_amdgcn_wave_barrier();

    wfft_dif4(z, s_tw, lane, +1.0f);   // unnormalized inverse, digit-reversed out

    const float invN = 1.0f / (float)N_;
    #pragma unroll
    for (int jb = 0; jb < 16; ++jb) {
        const int p = lane + 64 * jb;
        const int l = dr4(p);
        const float2 r = z[PD(p)];
        const size_t o = (((size_t)b * L_ + l) * E_ + e0) * H_ + h;
        Out[o] = r.x * invN;        // e0   -> Re
        Out[o + H_] = r.y * invN;   // e0+1 -> Im
    }
}

extern "C" void kernel_launch(void* const* d_in, const int* in_sizes, int n_in,
                              void* d_out, int out_size, void* d_ws, size_t ws_size,
                              hipStream_t stream) {
    const float* Q = (const float*)d_in[0];
    const float* K = (const float*)d_in[1];
    const float* V = (const float*)d_in[2];
    float* out = (float*)d_out;

    float* ws = (float*)d_ws;
    float* G     = ws;                                  // B*H*NF floats
    _Float16* Kh = (_Float16*)(ws + B_ * H_ * NF_);     // B*L*H*E halves (4 MB)

    hipMemsetAsync(G, 0, (size_t)B_ * H_ * NF_ * sizeof(float), stream);
    k_prep<<<(B_ * L_ * H_ + 255) / 256, 256, 0, stream>>>(K, Kh);
    k_qkfft<<<B_ * H_ * (L_ / 16), 256, 0, stream>>>(Q, Kh, G);
    k_vfft<<<B_ * H_ * (E_ / 8), 256, 0, stream>>>(V, G, out);
}